// Round 1
// baseline (477.992 us; speedup 1.0000x reference)
//
#include <hip/hip_runtime.h>
#include <math.h>

#define TPB 256
constexpr int kS = 7;
constexpr int kB = 2;
constexpr int kC = 20;
constexpr int kT = 32;
constexpr int kCH = kB * 5 + kC;      // 30 channels
constexpr int kCells = kS * kS;       // 49
constexpr int kImgF = kCells * kCH;   // 1470 floats per image
constexpr int IMGS = 4;               // 4 imgs/block -> 128 targets -> 2 lanes/target

// Block-wide sum reduction (result valid on thread 0 only).
__device__ __forceinline__ float block_reduce(float v, float* red) {
    #pragma unroll
    for (int off = 32; off > 0; off >>= 1)
        v += __shfl_down(v, off, 64);
    const int lane = threadIdx.x & 63;
    const int wave = threadIdx.x >> 6;
    if (lane == 0) red[wave] = v;
    __syncthreads();
    float s = 0.0f;
    if (threadIdx.x == 0) {
        #pragma unroll
        for (int w = 0; w < TPB / 64; w++) s += red[w];
    }
    return s;
}

// Single fused kernel.
// Phase 1: register-batched stream of the block's 4 images (all float4 loads
// issued before any consume -> full memory-level parallelism).
// Phase 2: TWO lanes per target; each lane loads its own box (float2) + half
// the classes; IoU and softmax halves combined with shfl_xor. Gather issue is
// HOISTED ahead of the phase-1 consume so the dependent-load latency overlaps.
// Finish: last-block-done reduction (device-scope atomics; counter zeroed by a
// 4-byte hipMemsetAsync graph node) replaces the old stage-2 launch.
__global__ __launch_bounds__(TPB) void yolo_fused(
    const float* __restrict__ outputs,
    const float4* __restrict__ tboxes,
    const int* __restrict__ tlabels,
    float* __restrict__ blocksums,
    unsigned int* __restrict__ counter,
    float* __restrict__ out,
    int n, float invn)
{
    __shared__ float red[TPB / 64];
    __shared__ int is_last;
    const int tid = threadIdx.x;
    const int img0 = blockIdx.x * IMGS;
    const int nimg = min(IMGS, n - img0);

    float local = 0.0f;
    const float kno = 0.5f / (float)(2 * kCells);   // LAMBDA_NOOBJ / 98

    // ---- pair decomposition for phase 2 ----
    const int pair = tid >> 1;        // target slot 0..127
    const int b = tid & 1;            // which predicted box this lane owns
    const bool has_tgt = pair < nimg * kT;
    float4 tb = make_float4(0.f, 0.f, 0.f, 0.f);
    int lab = 0;
    if (has_tgt) {                    // both lanes of a pair load the same 16B/4B
        tb = tboxes[(size_t)img0 * kT + pair];
        lab = tlabels[(size_t)img0 * kT + pair];
    }

    // ---- Phase 1a: issue the block's whole image stream (loads in flight) ----
    constexpr int NV4 = IMGS * kImgF / 4;           // 1470 float4s
    constexpr int FULL = NV4 / TPB;                 // 5 full rounds (1280)
    float4 vv[FULL];
    float4 vt = make_float4(0.f, 0.f, 0.f, 0.f);
    bool tok = false;
    const bool full_blk = (nimg == IMGS);
    if (full_blk) {
        const float4* src = reinterpret_cast<const float4*>(outputs + (size_t)img0 * kImgF);
        #pragma unroll
        for (int i = 0; i < FULL; i++) vv[i] = src[tid + i * TPB];   // all in flight
        const int tidx = tid + FULL * TPB;          // remainder: 190 float4s
        tok = tidx < NV4;
        if (tok) vt = src[tidx];
    }

    // ---- Phase 2a: compute gather addresses + issue cell gathers NOW, so the
    //      dependent-load latency overlaps the phase-1 consume. ----
    const float cellf = 1.0f / 7.0f;
    int gxi = 0, gyi = 0;
    float ox = 0.f, oy = 0.f;
    float2 g_xy = make_float2(0.f, 0.f), g_wh = make_float2(0.f, 0.f);
    float2 g_cf = make_float2(0.f, 0.f);
    float cls[10];
    #pragma unroll
    for (int j = 0; j < 10; j++) cls[j] = 0.f;
    if (has_tgt) {
        const int sub = pair >> 5;                  // image within block
        gxi = (int)(tb.x / cellf); gxi = min(max(gxi, 0), kS - 1);
        gyi = (int)(tb.y / cellf); gyi = min(max(gyi, 0), kS - 1);
        ox = (tb.x - (float)gxi * cellf) / cellf;
        oy = (tb.y - (float)gyi * cellf) / cellf;
        const float2* __restrict__ cell2 = reinterpret_cast<const float2*>(
            outputs + (size_t)(img0 + sub) * kImgF + (gyi * kS + gxi) * kCH);
        // my box: channels 4b..4b+3 (float2-aligned), conf pair at ch 8
        g_xy = cell2[2 * b + 0];
        g_wh = cell2[2 * b + 1];
        g_cf = cell2[4];
        // my class half: channels 10+10b .. 19+10b (5 float2s)
        #pragma unroll
        for (int j = 0; j < 5; j++) {
            const float2 c2 = cell2[5 + 5 * b + j];
            cls[2 * j] = c2.x; cls[2 * j + 1] = c2.y;
        }
    }

    // ---- Phase 1b: consume the stream (noobj conf^2 from registers) ----
    if (full_blk) {
        // channel of v.x for float4 idx is (4*idx)%30; step per round (4*TPB)%30==4
        int base = (4 * tid) % 30;
        #pragma unroll
        for (int i = 0; i < FULL; i++) {
            const float4 v = vv[i];
            if (base == 8)      local += kno * (v.x * v.x + v.y * v.y);
            else if (base == 6) local += kno * (v.z * v.z + v.w * v.w);
            base += 4; if (base >= 30) base -= 30;
        }
        if (tok) {
            if (base == 8)      local += kno * (vt.x * vt.x + vt.y * vt.y);
            else if (base == 6) local += kno * (vt.z * vt.z + vt.w * vt.w);
        }
    } else {
        // tail (never hit at N=16384): scalar
        const float* srcf = outputs + (size_t)img0 * kImgF;
        const int tot = nimg * kImgF;
        for (int i = tid; i < tot; i += TPB) {
            const float v = srcf[i];
            const int ch = i % kCH;
            if (ch == 8 || ch == 9) local += kno * v * v;
        }
    }

    // ---- Phase 2b: per-target terms from the pre-gathered registers ----
    if (has_tgt) {
        const float tx = tb.x, ty = tb.y, tw = tb.z, th = tb.w;

        // IoU of target vs my box (global coords)
        const float t_x1 = tx - tw * 0.5f, t_x2 = tx + tw * 0.5f;
        const float t_y1 = ty - th * 0.5f, t_y2 = ty + th * 0.5f;
        const float px = (g_xy.x + (float)gxi) * cellf;
        const float py = (g_xy.y + (float)gyi) * cellf;
        const float x21 = px - g_wh.x * 0.5f, x22 = px + g_wh.x * 0.5f;
        const float y21 = py - g_wh.y * 0.5f, y22 = py + g_wh.y * 0.5f;
        const float iw = fmaxf(fminf(t_x2, x22) - fmaxf(t_x1, x21), 0.0f);
        const float ih = fmaxf(fminf(t_y2, y22) - fmaxf(t_y1, y21), 0.0f);
        const float inter = iw * ih;
        const float uni = tw * th + g_wh.x * g_wh.y - inter;
        const float iou_mine = inter / fmaxf(uni, 1e-6f);
        const float iou_other = __shfl_xor(iou_mine, 1, 64);
        const float iou0 = b ? iou_other : iou_mine;
        const float iou1 = b ? iou_mine : iou_other;
        // jnp.argmax picks the FIRST max on ties -> strict '>' for index 1
        const int best = (iou1 > iou0) ? 1 : 0;

        if (b == best) {   // exactly one lane of the pair adds box+obj terms
            const float pw = fmaxf(g_wh.x, 1e-6f), ph = fmaxf(g_wh.y, 1e-6f);
            const float twc = fmaxf(tw, 1e-6f), thc = fmaxf(th, 1e-6f);
            const float dx = px - ox, dy = py - oy;
            const float dws = sqrtf(pw) - sqrtf(twc), dhs = sqrtf(ph) - sqrtf(thc);
            const float box_loss = dx * dx + dy * dy + dws * dws + dhs * dhs;
            const float dconf = (b ? g_cf.y : g_cf.x) - 1.0f;
            local += 5.0f * box_loss + dconf * dconf;
        }

        // class loss half: softmax max & denom combined exactly across the pair
        float mh = cls[0];
        #pragma unroll
        for (int j = 1; j < 10; j++) mh = fmaxf(mh, cls[j]);
        const float m = fmaxf(mh, __shfl_xor(mh, 1, 64));
        float sh = 0.0f;
        #pragma unroll
        for (int j = 0; j < 10; j++) { cls[j] = __expf(cls[j] - m); sh += cls[j]; }
        const float ssum = sh + __shfl_xor(sh, 1, 64);
        const float inv = 1.0f / ssum;
        float cl = 0.0f;
        const int labh = lab - 10 * b;              // my half covers classes 10b..10b+9
        #pragma unroll
        for (int j = 0; j < 10; j++) {
            const float d = cls[j] * inv - (j == labh ? 1.0f : 0.0f);
            cl += d * d;
        }
        local += cl * (1.0f / (float)kC);           // halves sum via block reduce
    }

    const float bsum = block_reduce(local, red);

    // ---- last-block-done final reduction (replaces stage-2 launch) ----
    if (tid == 0) {
        // agent-scope store: visible across XCDs (bypasses non-coherent L1/L2 path)
        __hip_atomic_store(&blocksums[blockIdx.x], bsum,
                           __ATOMIC_RELAXED, __HIP_MEMORY_SCOPE_AGENT);
        __threadfence();
        const unsigned int old = __hip_atomic_fetch_add(
            counter, 1u, __ATOMIC_ACQ_REL, __HIP_MEMORY_SCOPE_AGENT);
        is_last = (old == gridDim.x - 1) ? 1 : 0;
    }
    __syncthreads();   // also orders red[] reuse inside the second block_reduce
    if (is_last) {
        float l = 0.0f;
        const int nb = gridDim.x;
        for (int i = tid; i < nb; i += TPB)
            l += __hip_atomic_load(&blocksums[i],
                                   __ATOMIC_RELAXED, __HIP_MEMORY_SCOPE_AGENT);
        const float s = block_reduce(l, red);
        if (tid == 0) out[0] = s * invn;
    }
}

extern "C" void kernel_launch(void* const* d_in, const int* in_sizes, int n_in,
                              void* d_out, int out_size, void* d_ws, size_t ws_size,
                              hipStream_t stream)
{
    const float* outputs = (const float*)d_in[0];
    const float4* tboxes = (const float4*)d_in[1];
    const int* tlabels = (const int*)d_in[2];
    float* out = (float*)d_out;
    float* blocksums = (float*)d_ws;

    const int n = in_sizes[0] / kImgF;                 // 16384
    const int nblocks = (n + IMGS - 1) / IMGS;         // 4096

    unsigned int* counter =
        (unsigned int*)((char*)d_ws + (size_t)nblocks * sizeof(float));

    // 4-byte memset node (graph-capturable; NOT on the banned-API list).
    // If capture ever rejects this, fall back to a 1-thread init kernel.
    hipMemsetAsync(counter, 0, sizeof(unsigned int), stream);

    yolo_fused<<<nblocks, TPB, 0, stream>>>(outputs, tboxes, tlabels,
                                            blocksums, counter, out,
                                            n, 1.0f / (float)n);
}

// Round 2
// 163.746 us; speedup vs baseline: 2.9191x; 2.9191x over previous
//
#include <hip/hip_runtime.h>
#include <math.h>

#define TPB 256
constexpr int kS = 7;
constexpr int kB = 2;
constexpr int kC = 20;
constexpr int kT = 32;
constexpr int kCH = kB * 5 + kC;      // 30 channels
constexpr int kCells = kS * kS;       // 49
constexpr int kImgF = kCells * kCH;   // 1470 floats per image
constexpr int IMGS = 4;               // 4 imgs/block -> 128 targets -> 2 lanes/target

// Block-wide sum reduction (result valid on thread 0 only).
__device__ __forceinline__ float block_reduce(float v, float* red) {
    #pragma unroll
    for (int off = 32; off > 0; off >>= 1)
        v += __shfl_down(v, off, 64);
    const int lane = threadIdx.x & 63;
    const int wave = threadIdx.x >> 6;
    if (lane == 0) red[wave] = v;
    __syncthreads();
    float s = 0.0f;
    if (threadIdx.x == 0) {
        #pragma unroll
        for (int w = 0; w < TPB / 64; w++) s += red[w];
    }
    return s;
}

// Stage 1, split-grid: blocks [0, nbStream) are PURE STREAMERS (noobj conf^2
// over 4 images each, register-batched float4 stream, zero divergent work ->
// should run at fill-kernel BW). Blocks [nbStream, 2*nbStream) do ONLY the
// per-target terms (2 lanes/target, float2 gathers, IoU + softmax via
// shfl_xor). Isolating the divergent gather/epilogue work from the streaming
// blocks removes the per-block latency tail that kept stage1 ~2x off the BW
// floor. One partial per block; stage 2 reduces (4 us launch beats any
// cross-XCD coherent-counter fusion -- round-1 lesson: agent-scope ACQ_REL
// per block cost ~300 us on 8 non-coherent L2s).
__global__ __launch_bounds__(TPB) void yolo_stage1(
    const float* __restrict__ outputs,
    const float4* __restrict__ tboxes,
    const int* __restrict__ tlabels,
    float* __restrict__ blocksums,
    int n, int nbStream)
{
    __shared__ float red[TPB / 64];
    const int tid = threadIdx.x;
    float local = 0.0f;
    const float kno = 0.5f / (float)(2 * kCells);   // LAMBDA_NOOBJ / 98

    if (blockIdx.x < nbStream) {
        // ================= streaming blocks: noobj only =================
        const int img0 = blockIdx.x * IMGS;
        const int nimg = min(IMGS, n - img0);

        if (nimg == IMGS) {
            const float4* src = reinterpret_cast<const float4*>(outputs + (size_t)img0 * kImgF);
            constexpr int NV4 = IMGS * kImgF / 4;       // 1470
            constexpr int FULL = NV4 / TPB;             // 5 full rounds (1280)
            float4 vv[FULL];
            #pragma unroll
            for (int i = 0; i < FULL; i++) vv[i] = src[tid + i * TPB];   // all in flight
            const int tidx = tid + FULL * TPB;          // remainder: 190 float4s
            float4 vt = make_float4(0.f, 0.f, 0.f, 0.f);
            const bool tok = tidx < NV4;
            if (tok) vt = src[tidx];

            // channel of v.x for float4 idx is (4*idx)%30; step per round (4*TPB)%30==4
            int base = (4 * tid) % 30;
            #pragma unroll
            for (int i = 0; i < FULL; i++) {
                const float4 v = vv[i];
                if (base == 8)      local += kno * (v.x * v.x + v.y * v.y);
                else if (base == 6) local += kno * (v.z * v.z + v.w * v.w);
                base += 4; if (base >= 30) base -= 30;
            }
            if (tok) {
                if (base == 8)      local += kno * (vt.x * vt.x + vt.y * vt.y);
                else if (base == 6) local += kno * (vt.z * vt.z + vt.w * vt.w);
            }
        } else if (nimg > 0) {
            // tail (never hit at N=16384): scalar
            const float* srcf = outputs + (size_t)img0 * kImgF;
            const int tot = nimg * kImgF;
            for (int i = tid; i < tot; i += TPB) {
                const float v = srcf[i];
                const int ch = i % kCH;
                if (ch == 8 || ch == 9) local += kno * v * v;
            }
        }
    } else {
        // ================= target blocks: per-target terms only =================
        const int tblk = blockIdx.x - nbStream;
        const int img0 = tblk * IMGS;
        const int nimg = min(IMGS, n - img0);

        const int pair = tid >> 1;        // target slot 0..127
        const int b = tid & 1;            // which predicted box this lane owns
        const bool has_tgt = (nimg > 0) && (pair < nimg * kT);

        if (has_tgt) {
            const float4 tb = tboxes[(size_t)img0 * kT + pair];  // both lanes same 16B
            const int lab = tlabels[(size_t)img0 * kT + pair];
            const int sub = pair >> 5;                  // image within block
            const float cellf = 1.0f / 7.0f;
            const float tx = tb.x, ty = tb.y, tw = tb.z, th = tb.w;

            int gxi = (int)(tx / cellf); gxi = min(max(gxi, 0), kS - 1);
            int gyi = (int)(ty / cellf); gyi = min(max(gyi, 0), kS - 1);
            const float ox = (tx - (float)gxi * cellf) / cellf;
            const float oy = (ty - (float)gyi * cellf) / cellf;
            const float2* __restrict__ cell2 = reinterpret_cast<const float2*>(
                outputs + (size_t)(img0 + sub) * kImgF + (gyi * kS + gxi) * kCH);

            // my box: channels 4b..4b+3 (float2-aligned), conf pair at ch 8
            const float2 xy = cell2[2 * b + 0];
            const float2 wh = cell2[2 * b + 1];
            const float2 cf = cell2[4];
            // my class half: channels 10+10b .. 19+10b (5 float2s)
            float cls[10];
            #pragma unroll
            for (int j = 0; j < 5; j++) {
                const float2 c2 = cell2[5 + 5 * b + j];
                cls[2 * j] = c2.x; cls[2 * j + 1] = c2.y;
            }

            // IoU of target vs my box (global coords)
            const float t_x1 = tx - tw * 0.5f, t_x2 = tx + tw * 0.5f;
            const float t_y1 = ty - th * 0.5f, t_y2 = ty + th * 0.5f;
            const float px = (xy.x + (float)gxi) * cellf;
            const float py = (xy.y + (float)gyi) * cellf;
            const float x21 = px - wh.x * 0.5f, x22 = px + wh.x * 0.5f;
            const float y21 = py - wh.y * 0.5f, y22 = py + wh.y * 0.5f;
            const float iw = fmaxf(fminf(t_x2, x22) - fmaxf(t_x1, x21), 0.0f);
            const float ih = fmaxf(fminf(t_y2, y22) - fmaxf(t_y1, y21), 0.0f);
            const float inter = iw * ih;
            const float uni = tw * th + wh.x * wh.y - inter;
            const float iou_mine = inter / fmaxf(uni, 1e-6f);
            const float iou_other = __shfl_xor(iou_mine, 1, 64);
            const float iou0 = b ? iou_other : iou_mine;
            const float iou1 = b ? iou_mine : iou_other;
            // jnp.argmax picks the FIRST max on ties -> strict '>' for index 1
            const int best = (iou1 > iou0) ? 1 : 0;

            if (b == best) {   // exactly one lane of the pair adds box+obj terms
                const float pw = fmaxf(wh.x, 1e-6f), ph = fmaxf(wh.y, 1e-6f);
                const float twc = fmaxf(tw, 1e-6f), thc = fmaxf(th, 1e-6f);
                const float dx = px - ox, dy = py - oy;
                const float dws = sqrtf(pw) - sqrtf(twc), dhs = sqrtf(ph) - sqrtf(thc);
                const float box_loss = dx * dx + dy * dy + dws * dws + dhs * dhs;
                const float dconf = (b ? cf.y : cf.x) - 1.0f;
                local += 5.0f * box_loss + dconf * dconf;
            }

            // class loss half: softmax max & denom combined exactly across the pair
            float mh = cls[0];
            #pragma unroll
            for (int j = 1; j < 10; j++) mh = fmaxf(mh, cls[j]);
            const float m = fmaxf(mh, __shfl_xor(mh, 1, 64));
            float sh = 0.0f;
            #pragma unroll
            for (int j = 0; j < 10; j++) { cls[j] = __expf(cls[j] - m); sh += cls[j]; }
            const float ssum = sh + __shfl_xor(sh, 1, 64);
            const float inv = 1.0f / ssum;
            float cl = 0.0f;
            const int labh = lab - 10 * b;              // my half covers classes 10b..10b+9
            #pragma unroll
            for (int j = 0; j < 10; j++) {
                const float d = cls[j] * inv - (j == labh ? 1.0f : 0.0f);
                cl += d * d;
            }
            local += cl * (1.0f / (float)kC);           // halves sum via block reduce
        }
    }

    const float bsum = block_reduce(local, red);
    if (tid == 0) blocksums[blockIdx.x] = bsum;
}

// Stage 2: reduce per-block partials, write mean.
__global__ __launch_bounds__(TPB) void yolo_stage2(
    const float* __restrict__ blocksums, int nblocks, float invn,
    float* __restrict__ out)
{
    __shared__ float red[TPB / 64];
    float local = 0.0f;
    for (int i = threadIdx.x; i < nblocks; i += TPB) local += blocksums[i];
    const float s = block_reduce(local, red);
    if (threadIdx.x == 0) out[0] = s * invn;
}

extern "C" void kernel_launch(void* const* d_in, const int* in_sizes, int n_in,
                              void* d_out, int out_size, void* d_ws, size_t ws_size,
                              hipStream_t stream)
{
    const float* outputs = (const float*)d_in[0];
    const float4* tboxes = (const float4*)d_in[1];
    const int* tlabels = (const int*)d_in[2];
    float* out = (float*)d_out;
    float* blocksums = (float*)d_ws;

    const int n = in_sizes[0] / kImgF;                 // 16384
    const int nbStream = (n + IMGS - 1) / IMGS;        // 4096
    const int nblocks = 2 * nbStream;                  // streamers + target blocks

    yolo_stage1<<<nblocks, TPB, 0, stream>>>(outputs, tboxes, tlabels, blocksums,
                                             n, nbStream);
    yolo_stage2<<<1, TPB, 0, stream>>>(blocksums, nblocks, 1.0f / (float)n, out);
}

// Round 3
// 156.573 us; speedup vs baseline: 3.0528x; 1.0458x over previous
//
#include <hip/hip_runtime.h>
#include <math.h>

#define TPB 256
constexpr int kS = 7;
constexpr int kB = 2;
constexpr int kC = 20;
constexpr int kT = 32;
constexpr int kCH = kB * 5 + kC;      // 30 channels
constexpr int kCells = kS * kS;       // 49
constexpr int kImgF = kCells * kCH;   // 1470 floats per image
constexpr int IMGS = 8;               // 8 imgs/block -> 256 targets -> 2 lanes/target x 2 slots

// Block-wide sum reduction (result valid on thread 0 only).
__device__ __forceinline__ float block_reduce(float v, float* red) {
    #pragma unroll
    for (int off = 32; off > 0; off >>= 1)
        v += __shfl_down(v, off, 64);
    const int lane = threadIdx.x & 63;
    const int wave = threadIdx.x >> 6;
    if (lane == 0) red[wave] = v;
    __syncthreads();
    float s = 0.0f;
    if (threadIdx.x == 0) {
        #pragma unroll
        for (int w = 0; w < TPB / 64; w++) s += red[w];
    }
    return s;
}

// Stage 1 (round-0 structure, IMGS doubled to 8).
// Phase 1: register-batched stream of the block's 8 images (all float4 loads
// issued before any consume -> full MLP). Phase 2: TWO lanes per target, TWO
// target slots per pair (slots pair and pair+128); each lane loads its own box
// (float2) + half the classes, IoU and softmax halves combined with shfl_xor.
// Rationale: per-block tail (gather latency + softmax + reduce) is the ~2.4x
// slack over the BW floor; doubling IMGS halves the number of tails while the
// gathers stay L1-hot (round-2 lesson: splitting gathers from the stream cost
// +10 us of re-fetch traffic). One partial per block; tiny stage-2 reduces
// (round-1 lesson: coherent-counter fusion costs ~90 ns x nblocks serialized).
__global__ __launch_bounds__(TPB) void yolo_stage1(
    const float* __restrict__ outputs,
    const float4* __restrict__ tboxes,
    const int* __restrict__ tlabels,
    float* __restrict__ blocksums,
    int n)
{
    __shared__ float red[TPB / 64];
    const int tid = threadIdx.x;
    const int img0 = blockIdx.x * IMGS;
    const int nimg = min(IMGS, n - img0);

    float local = 0.0f;
    const float kno = 0.5f / (float)(2 * kCells);   // LAMBDA_NOOBJ / 98

    // ---- Phase 1: stream block's images, noobj conf^2 from registers ----
    if (nimg == IMGS) {
        const float4* src = reinterpret_cast<const float4*>(outputs + (size_t)img0 * kImgF);
        constexpr int NV4 = IMGS * kImgF / 4;       // 2940
        constexpr int FULL = NV4 / TPB;             // 11 full rounds (2816)
        float4 vv[FULL];
        #pragma unroll
        for (int i = 0; i < FULL; i++) vv[i] = src[tid + i * TPB];   // all in flight
        const int tidx = tid + FULL * TPB;          // remainder: 124 float4s
        float4 vt = make_float4(0.f, 0.f, 0.f, 0.f);
        const bool tok = tidx < NV4;
        if (tok) vt = src[tidx];

        // channel of v.x for float4 idx is (4*idx)%30; step per round (4*TPB)%30==4
        int base = (4 * tid) % 30;
        #pragma unroll
        for (int i = 0; i < FULL; i++) {
            const float4 v = vv[i];
            if (base == 8)      local += kno * (v.x * v.x + v.y * v.y);
            else if (base == 6) local += kno * (v.z * v.z + v.w * v.w);
            base += 4; if (base >= 30) base -= 30;
        }
        if (tok) {
            if (base == 8)      local += kno * (vt.x * vt.x + vt.y * vt.y);
            else if (base == 6) local += kno * (vt.z * vt.z + vt.w * vt.w);
        }
    } else if (nimg > 0) {
        // tail (never hit at N=16384): scalar
        const float* srcf = outputs + (size_t)img0 * kImgF;
        const int tot = nimg * kImgF;
        for (int i = tid; i < tot; i += TPB) {
            const float v = srcf[i];
            const int ch = i % kCH;
            if (ch == 8 || ch == 9) local += kno * v * v;
        }
    }

    // ---- Phase 2: per-target terms, 2 lanes/target, 2 slots/pair ----
    const int pair = tid >> 1;            // 0..127
    const int b = tid & 1;                // which predicted box this lane owns
    #pragma unroll
    for (int ts = 0; ts < 2; ts++) {
        const int tgt = pair + 128 * ts;  // target slot 0..255 within block
        if (tgt >= nimg * kT) continue;   // uniform across the pair (both lanes same tgt)

        const float4 tb = tboxes[(size_t)img0 * kT + tgt];   // both lanes same 16B
        const int lab = tlabels[(size_t)img0 * kT + tgt];
        const int sub = tgt >> 5;                   // image within block (0..7)
        const float cellf = 1.0f / 7.0f;
        const float tx = tb.x, ty = tb.y, tw = tb.z, th = tb.w;

        int gxi = (int)(tx / cellf); gxi = min(max(gxi, 0), kS - 1);
        int gyi = (int)(ty / cellf); gyi = min(max(gyi, 0), kS - 1);
        const float ox = (tx - (float)gxi * cellf) / cellf;
        const float oy = (ty - (float)gyi * cellf) / cellf;
        const float2* __restrict__ cell2 = reinterpret_cast<const float2*>(
            outputs + (size_t)(img0 + sub) * kImgF + (gyi * kS + gxi) * kCH);

        // my box: channels 4b..4b+3 (float2-aligned), conf pair at ch 8
        const float2 xy = cell2[2 * b + 0];
        const float2 wh = cell2[2 * b + 1];
        const float2 cf = cell2[4];
        // my class half: channels 10+10b .. 19+10b (5 float2s)
        float cls[10];
        #pragma unroll
        for (int j = 0; j < 5; j++) {
            const float2 c2 = cell2[5 + 5 * b + j];
            cls[2 * j] = c2.x; cls[2 * j + 1] = c2.y;
        }

        // IoU of target vs my box (global coords)
        const float t_x1 = tx - tw * 0.5f, t_x2 = tx + tw * 0.5f;
        const float t_y1 = ty - th * 0.5f, t_y2 = ty + th * 0.5f;
        const float px = (xy.x + (float)gxi) * cellf;
        const float py = (xy.y + (float)gyi) * cellf;
        const float x21 = px - wh.x * 0.5f, x22 = px + wh.x * 0.5f;
        const float y21 = py - wh.y * 0.5f, y22 = py + wh.y * 0.5f;
        const float iw = fmaxf(fminf(t_x2, x22) - fmaxf(t_x1, x21), 0.0f);
        const float ih = fmaxf(fminf(t_y2, y22) - fmaxf(t_y1, y21), 0.0f);
        const float inter = iw * ih;
        const float uni = tw * th + wh.x * wh.y - inter;
        const float iou_mine = inter / fmaxf(uni, 1e-6f);
        const float iou_other = __shfl_xor(iou_mine, 1, 64);
        const float iou0 = b ? iou_other : iou_mine;
        const float iou1 = b ? iou_mine : iou_other;
        // jnp.argmax picks the FIRST max on ties -> strict '>' for index 1
        const int best = (iou1 > iou0) ? 1 : 0;

        if (b == best) {   // exactly one lane of the pair adds box+obj terms
            const float pw = fmaxf(wh.x, 1e-6f), ph = fmaxf(wh.y, 1e-6f);
            const float twc = fmaxf(tw, 1e-6f), thc = fmaxf(th, 1e-6f);
            const float dx = px - ox, dy = py - oy;
            const float dws = sqrtf(pw) - sqrtf(twc), dhs = sqrtf(ph) - sqrtf(thc);
            const float box_loss = dx * dx + dy * dy + dws * dws + dhs * dhs;
            const float dconf = (b ? cf.y : cf.x) - 1.0f;
            local += 5.0f * box_loss + dconf * dconf;
        }

        // class loss half: softmax max & denom combined exactly across the pair
        float mh = cls[0];
        #pragma unroll
        for (int j = 1; j < 10; j++) mh = fmaxf(mh, cls[j]);
        const float m = fmaxf(mh, __shfl_xor(mh, 1, 64));
        float sh = 0.0f;
        #pragma unroll
        for (int j = 0; j < 10; j++) { cls[j] = __expf(cls[j] - m); sh += cls[j]; }
        const float ssum = sh + __shfl_xor(sh, 1, 64);
        const float inv = 1.0f / ssum;
        float cl = 0.0f;
        const int labh = lab - 10 * b;              // my half covers classes 10b..10b+9
        #pragma unroll
        for (int j = 0; j < 10; j++) {
            const float d = cls[j] * inv - (j == labh ? 1.0f : 0.0f);
            cl += d * d;
        }
        local += cl * (1.0f / (float)kC);           // halves sum via block reduce
    }

    const float bsum = block_reduce(local, red);
    if (tid == 0) blocksums[blockIdx.x] = bsum;
}

// Stage 2: reduce per-block partials, write mean.
__global__ __launch_bounds__(TPB) void yolo_stage2(
    const float* __restrict__ blocksums, int nblocks, float invn,
    float* __restrict__ out)
{
    __shared__ float red[TPB / 64];
    float local = 0.0f;
    for (int i = threadIdx.x; i < nblocks; i += TPB) local += blocksums[i];
    const float s = block_reduce(local, red);
    if (threadIdx.x == 0) out[0] = s * invn;
}

extern "C" void kernel_launch(void* const* d_in, const int* in_sizes, int n_in,
                              void* d_out, int out_size, void* d_ws, size_t ws_size,
                              hipStream_t stream)
{
    const float* outputs = (const float*)d_in[0];
    const float4* tboxes = (const float4*)d_in[1];
    const int* tlabels = (const int*)d_in[2];
    float* out = (float*)d_out;
    float* blocksums = (float*)d_ws;

    const int n = in_sizes[0] / kImgF;                 // 16384
    const int nblocks = (n + IMGS - 1) / IMGS;         // 2048

    yolo_stage1<<<nblocks, TPB, 0, stream>>>(outputs, tboxes, tlabels, blocksums, n);
    yolo_stage2<<<1, TPB, 0, stream>>>(blocksums, nblocks, 1.0f / (float)n, out);
}

// Round 4
// 152.402 us; speedup vs baseline: 3.1364x; 1.0274x over previous
//
#include <hip/hip_runtime.h>
#include <math.h>

#define TPB 256
constexpr int kS = 7;
constexpr int kB = 2;
constexpr int kC = 20;
constexpr int kT = 32;
constexpr int kCH = kB * 5 + kC;      // 30 channels
constexpr int kCells = kS * kS;       // 49
constexpr int kImgF = kCells * kCH;   // 1470 floats per image
constexpr int IMGS = 4;               // 4 imgs/block -> 128 targets -> 2 lanes/target

// Block-wide sum reduction (result valid on thread 0 only).
__device__ __forceinline__ float block_reduce(float v, float* red) {
    #pragma unroll
    for (int off = 32; off > 0; off >>= 1)
        v += __shfl_down(v, off, 64);
    const int lane = threadIdx.x & 63;
    const int wave = threadIdx.x >> 6;
    if (lane == 0) red[wave] = v;
    __syncthreads();
    float s = 0.0f;
    if (threadIdx.x == 0) {
        #pragma unroll
        for (int w = 0; w < TPB / 64; w++) s += red[w];
    }
    return s;
}

// Stage 1 = round-0 structure + LDS staging of the streamed images.
// Phase 1: register-batched float4 stream of the block's 4 images (5-deep
// batch, VGPR-light -> full 32 waves/CU worth of TLP does the latency hiding;
// round-3 lesson: deeper batches cost occupancy and regress). Every streamed
// float4 is ALSO written to LDS (contiguous ds_write_b128, conflict-free).
// Phase 2: per-target terms, 2 lanes/target; cell gathers now read LDS
// instead of global (round-0's tail paid a 2nd dependent global hop: block
// streams 94KB through 32KB L1 and 8 blocks share a 4MB L2 slice, so cell
// lines were mostly evicted by consume time). Only remaining global load in
// the tail is tb, issued at block start (L3-hot, overlapped with stream).
// One partial per block; tiny stage-2 kernel reduces (round-1 lesson:
// coherent-counter fusion serializes on 8 non-coherent L2s, +300us).
__global__ __launch_bounds__(TPB) void yolo_stage1(
    const float* __restrict__ outputs,
    const float4* __restrict__ tboxes,
    const int* __restrict__ tlabels,
    float* __restrict__ blocksums,
    int n)
{
    __shared__ float red[TPB / 64];
    __shared__ __align__(16) float simg[IMGS * kImgF];   // 23520 B
    const int tid = threadIdx.x;
    const int img0 = blockIdx.x * IMGS;
    const int nimg = min(IMGS, n - img0);

    float local = 0.0f;
    const float kno = 0.5f / (float)(2 * kCells);   // LAMBDA_NOOBJ / 98

    // ---- pair decomposition; tb/lab issued FIRST (independent of stream) ----
    const int pair = tid >> 1;        // target slot 0..127
    const int b = tid & 1;            // which predicted box this lane owns
    const bool has_tgt = pair < nimg * kT;
    float4 tb = make_float4(0.f, 0.f, 0.f, 0.f);
    int lab = 0;
    if (has_tgt) {                    // both lanes of a pair load the same 16B/4B
        tb = tboxes[(size_t)img0 * kT + pair];
        lab = tlabels[(size_t)img0 * kT + pair];
    }

    // ---- Phase 1: stream images -> registers -> LDS; noobj conf^2 ----
    if (nimg == IMGS) {
        const float4* src = reinterpret_cast<const float4*>(outputs + (size_t)img0 * kImgF);
        constexpr int NV4 = IMGS * kImgF / 4;       // 1470
        constexpr int FULL = NV4 / TPB;             // 5 full rounds (1280)
        float4 vv[FULL];
        #pragma unroll
        for (int i = 0; i < FULL; i++) vv[i] = src[tid + i * TPB];   // all in flight
        const int tidx = tid + FULL * TPB;          // remainder: 190 float4s
        float4 vt = make_float4(0.f, 0.f, 0.f, 0.f);
        const bool tok = tidx < NV4;
        if (tok) vt = src[tidx];

        // stage to LDS (contiguous float4 stores, conflict-free)
        #pragma unroll
        for (int i = 0; i < FULL; i++)
            *reinterpret_cast<float4*>(&simg[4 * (tid + i * TPB)]) = vv[i];
        if (tok)
            *reinterpret_cast<float4*>(&simg[4 * tidx]) = vt;

        // channel of v.x for float4 idx is (4*idx)%30; step per round (4*TPB)%30==4
        int base = (4 * tid) % 30;
        #pragma unroll
        for (int i = 0; i < FULL; i++) {
            const float4 v = vv[i];
            if (base == 8)      local += kno * (v.x * v.x + v.y * v.y);
            else if (base == 6) local += kno * (v.z * v.z + v.w * v.w);
            base += 4; if (base >= 30) base -= 30;
        }
        if (tok) {
            if (base == 8)      local += kno * (vt.x * vt.x + vt.y * vt.y);
            else if (base == 6) local += kno * (vt.z * vt.z + vt.w * vt.w);
        }
    } else if (nimg > 0) {
        // tail (never hit at N=16384): scalar, still stages to LDS
        const float* srcf = outputs + (size_t)img0 * kImgF;
        const int tot = nimg * kImgF;
        for (int i = tid; i < tot; i += TPB) {
            const float v = srcf[i];
            simg[i] = v;
            const int ch = i % kCH;
            if (ch == 8 || ch == 9) local += kno * v * v;
        }
    }

    __syncthreads();   // LDS image tiles ready for phase-2 gathers

    // ---- Phase 2: per-target terms, cell fragments read from LDS ----
    if (has_tgt) {
        const int sub = pair >> 5;                  // image within block
        const float cellf = 1.0f / 7.0f;
        const float tx = tb.x, ty = tb.y, tw = tb.z, th = tb.w;

        int gxi = (int)(tx / cellf); gxi = min(max(gxi, 0), kS - 1);
        int gyi = (int)(ty / cellf); gyi = min(max(gyi, 0), kS - 1);
        const float ox = (tx - (float)gxi * cellf) / cellf;
        const float oy = (ty - (float)gyi * cellf) / cellf;
        // 8-byte aligned: (sub*1470 + cell*30)*4B is a multiple of 8
        const float2* __restrict__ cell2 = reinterpret_cast<const float2*>(
            &simg[sub * kImgF + (gyi * kS + gxi) * kCH]);

        // my box: channels 4b..4b+3 (float2-aligned), conf pair at ch 8
        const float2 xy = cell2[2 * b + 0];
        const float2 wh = cell2[2 * b + 1];
        const float2 cf = cell2[4];
        // my class half: channels 10+10b .. 19+10b (5 float2s)
        float cls[10];
        #pragma unroll
        for (int j = 0; j < 5; j++) {
            const float2 c2 = cell2[5 + 5 * b + j];
            cls[2 * j] = c2.x; cls[2 * j + 1] = c2.y;
        }

        // IoU of target vs my box (global coords)
        const float t_x1 = tx - tw * 0.5f, t_x2 = tx + tw * 0.5f;
        const float t_y1 = ty - th * 0.5f, t_y2 = ty + th * 0.5f;
        const float px = (xy.x + (float)gxi) * cellf;
        const float py = (xy.y + (float)gyi) * cellf;
        const float x21 = px - wh.x * 0.5f, x22 = px + wh.x * 0.5f;
        const float y21 = py - wh.y * 0.5f, y22 = py + wh.y * 0.5f;
        const float iw = fmaxf(fminf(t_x2, x22) - fmaxf(t_x1, x21), 0.0f);
        const float ih = fmaxf(fminf(t_y2, y22) - fmaxf(t_y1, y21), 0.0f);
        const float inter = iw * ih;
        const float uni = tw * th + wh.x * wh.y - inter;
        const float iou_mine = inter / fmaxf(uni, 1e-6f);
        const float iou_other = __shfl_xor(iou_mine, 1, 64);
        const float iou0 = b ? iou_other : iou_mine;
        const float iou1 = b ? iou_mine : iou_other;
        // jnp.argmax picks the FIRST max on ties -> strict '>' for index 1
        const int best = (iou1 > iou0) ? 1 : 0;

        if (b == best) {   // exactly one lane of the pair adds box+obj terms
            const float pw = fmaxf(wh.x, 1e-6f), ph = fmaxf(wh.y, 1e-6f);
            const float twc = fmaxf(tw, 1e-6f), thc = fmaxf(th, 1e-6f);
            const float dx = px - ox, dy = py - oy;
            const float dws = sqrtf(pw) - sqrtf(twc), dhs = sqrtf(ph) - sqrtf(thc);
            const float box_loss = dx * dx + dy * dy + dws * dws + dhs * dhs;
            const float dconf = (b ? cf.y : cf.x) - 1.0f;
            local += 5.0f * box_loss + dconf * dconf;
        }

        // class loss half: softmax max & denom combined exactly across the pair
        float mh = cls[0];
        #pragma unroll
        for (int j = 1; j < 10; j++) mh = fmaxf(mh, cls[j]);
        const float m = fmaxf(mh, __shfl_xor(mh, 1, 64));
        float sh = 0.0f;
        #pragma unroll
        for (int j = 0; j < 10; j++) { cls[j] = __expf(cls[j] - m); sh += cls[j]; }
        const float ssum = sh + __shfl_xor(sh, 1, 64);
        const float inv = 1.0f / ssum;
        float cl = 0.0f;
        const int labh = lab - 10 * b;              // my half covers classes 10b..10b+9
        #pragma unroll
        for (int j = 0; j < 10; j++) {
            const float d = cls[j] * inv - (j == labh ? 1.0f : 0.0f);
            cl += d * d;
        }
        local += cl * (1.0f / (float)kC);           // halves sum via block reduce
    }

    const float bsum = block_reduce(local, red);
    if (tid == 0) blocksums[blockIdx.x] = bsum;
}

// Stage 2: reduce per-block partials, write mean.
__global__ __launch_bounds__(TPB) void yolo_stage2(
    const float* __restrict__ blocksums, int nblocks, float invn,
    float* __restrict__ out)
{
    __shared__ float red[TPB / 64];
    float local = 0.0f;
    for (int i = threadIdx.x; i < nblocks; i += TPB) local += blocksums[i];
    const float s = block_reduce(local, red);
    if (threadIdx.x == 0) out[0] = s * invn;
}

extern "C" void kernel_launch(void* const* d_in, const int* in_sizes, int n_in,
                              void* d_out, int out_size, void* d_ws, size_t ws_size,
                              hipStream_t stream)
{
    const float* outputs = (const float*)d_in[0];
    const float4* tboxes = (const float4*)d_in[1];
    const int* tlabels = (const int*)d_in[2];
    float* out = (float*)d_out;
    float* blocksums = (float*)d_ws;

    const int n = in_sizes[0] / kImgF;                 // 16384
    const int nblocks = (n + IMGS - 1) / IMGS;         // 4096

    yolo_stage1<<<nblocks, TPB, 0, stream>>>(outputs, tboxes, tlabels, blocksums, n);
    yolo_stage2<<<1, TPB, 0, stream>>>(blocksums, nblocks, 1.0f / (float)n, out);
}